// Round 11
// baseline (2953.962 us; speedup 1.0000x reference)
//
#include <hip/hip_runtime.h>
#include <hip/hip_bf16.h>

// BinaryMoSLinear: B=4, S=2048 -> N=8192 rows; H=O=4096; E=4.
#define H_DIM 4096
#define O_DIM 4096
#define N_ROWS 8192

typedef __bf16 bf16x8 __attribute__((ext_vector_type(8)));
typedef float  f32x4  __attribute__((ext_vector_type(4)));

__device__ __forceinline__ unsigned short f32_bf16_rne(float f) {
    unsigned int u = __builtin_bit_cast(unsigned int, f);
    u += 0x7FFFu + ((u >> 16) & 1u);
    return (unsigned short)(u >> 16);
}

__device__ __forceinline__ void gload_lds16(const unsigned short* g, unsigned short* l) {
    __builtin_amdgcn_global_load_lds((const __attribute__((address_space(1))) void*)g,
                                     (__attribute__((address_space(3))) void*)l,
                                     16, 0, 0);
}

// ---------------------------------------------------------------------------
// Fused pre-kernel (R10, kept): blocks [0, SIGN_BLKS) do sign(weight)->bf16;
// blocks [SIGN_BLKS, SIGN_BLKS+N_ROWS) do router softmax + xs scale.
// ---------------------------------------------------------------------------
#define SIGN_BLKS ((O_DIM * H_DIM) / (256 * 8))   // 8192

__global__ void __launch_bounds__(256) pre_kernel(
    const float* __restrict__ w,  unsigned short* __restrict__ bw,
    const float* __restrict__ x,  const float* __restrict__ gate_w,
    const float* __restrict__ ics, float* __restrict__ rw_out,
    unsigned short* __restrict__ xs_out)
{
    const int t = threadIdx.x;

    if (blockIdx.x < SIGN_BLKS) {
        size_t i = ((size_t)blockIdx.x * 256 + t) * 8;
        float4 a = *reinterpret_cast<const float4*>(w + i);
        float4 b = *reinterpret_cast<const float4*>(w + i + 4);
        ushort4 o0, o1;
        o0.x = a.x > 0.f ? 0x3F80 : (a.x < 0.f ? 0xBF80 : 0);
        o0.y = a.y > 0.f ? 0x3F80 : (a.y < 0.f ? 0xBF80 : 0);
        o0.z = a.z > 0.f ? 0x3F80 : (a.z < 0.f ? 0xBF80 : 0);
        o0.w = a.w > 0.f ? 0x3F80 : (a.w < 0.f ? 0xBF80 : 0);
        o1.x = b.x > 0.f ? 0x3F80 : (b.x < 0.f ? 0xBF80 : 0);
        o1.y = b.y > 0.f ? 0x3F80 : (b.y < 0.f ? 0xBF80 : 0);
        o1.z = b.z > 0.f ? 0x3F80 : (b.z < 0.f ? 0xBF80 : 0);
        o1.w = b.w > 0.f ? 0x3F80 : (b.w < 0.f ? 0xBF80 : 0);
        uint4 pack;
        pack.x = (unsigned)o0.x | ((unsigned)o0.y << 16);
        pack.y = (unsigned)o0.z | ((unsigned)o0.w << 16);
        pack.z = (unsigned)o1.x | ((unsigned)o1.y << 16);
        pack.w = (unsigned)o1.z | ((unsigned)o1.w << 16);
        *reinterpret_cast<uint4*>(bw + i) = pack;
        return;
    }

    __shared__ float red[4][4];
    const int n = blockIdx.x - SIGN_BLKS;
    const float* xr = x + (size_t)n * H_DIM;

    float4 xv[4];
    float lg[4] = {0.f, 0.f, 0.f, 0.f};
#pragma unroll
    for (int c = 0; c < 4; ++c) {
        const int idx = c * 1024 + t * 4;
        xv[c] = *reinterpret_cast<const float4*>(xr + idx);
#pragma unroll
        for (int e = 0; e < 4; ++e) {
            float4 g = *reinterpret_cast<const float4*>(gate_w + e * H_DIM + idx);
            lg[e] += xv[c].x * g.x + xv[c].y * g.y + xv[c].z * g.z + xv[c].w * g.w;
        }
    }
#pragma unroll
    for (int e = 0; e < 4; ++e) {
#pragma unroll
        for (int off = 1; off < 64; off <<= 1)
            lg[e] += __shfl_xor(lg[e], off, 64);
    }
    if ((t & 63) == 0) {
        const int w_ = t >> 6;
        red[w_][0] = lg[0]; red[w_][1] = lg[1]; red[w_][2] = lg[2]; red[w_][3] = lg[3];
    }
    __syncthreads();
    const float l0 = red[0][0] + red[1][0] + red[2][0] + red[3][0];
    const float l1 = red[0][1] + red[1][1] + red[2][1] + red[3][1];
    const float l2 = red[0][2] + red[1][2] + red[2][2] + red[3][2];
    const float l3 = red[0][3] + red[1][3] + red[2][3] + red[3][3];
    const float m  = fmaxf(fmaxf(l0, l1), fmaxf(l2, l3));
    const float p0 = expf(l0 - m), p1 = expf(l1 - m), p2 = expf(l2 - m), p3 = expf(l3 - m);
    const float inv = 1.f / (p0 + p1 + p2 + p3);
    const float w0 = p0 * inv, w1 = p1 * inv, w2 = p2 * inv, w3 = p3 * inv;
    if (t == 0) {
        float4 wv = make_float4(w0, w1, w2, w3);
        *reinterpret_cast<float4*>(rw_out + (size_t)n * 4) = wv;
    }
#pragma unroll
    for (int c = 0; c < 4; ++c) {
        const int idx = c * 1024 + t * 4;
        float4 i0 = *reinterpret_cast<const float4*>(ics + 0 * H_DIM + idx);
        float4 i1 = *reinterpret_cast<const float4*>(ics + 1 * H_DIM + idx);
        float4 i2 = *reinterpret_cast<const float4*>(ics + 2 * H_DIM + idx);
        float4 i3 = *reinterpret_cast<const float4*>(ics + 3 * H_DIM + idx);
        const float sx = w0 * i0.x + w1 * i1.x + w2 * i2.x + w3 * i3.x;
        const float sy = w0 * i0.y + w1 * i1.y + w2 * i2.y + w3 * i3.y;
        const float sz = w0 * i0.z + w1 * i1.z + w2 * i2.z + w3 * i3.z;
        const float sw = w0 * i0.w + w1 * i1.w + w2 * i2.w + w3 * i3.w;
        ushort4 o;
        o.x = f32_bf16_rne(xv[c].x * sx);
        o.y = f32_bf16_rne(xv[c].y * sy);
        o.z = f32_bf16_rne(xv[c].z * sz);
        o.w = f32_bf16_rne(xv[c].w * sw);
        *reinterpret_cast<ushort4*>(xs_out + (size_t)n * H_DIM + idx) = o;
    }
}

// ---------------------------------------------------------------------------
// Kernel 3: C = (xs @ bw^T) * (rw @ ocs) + bias  — R8 structure + ANTI-PHASE
// wave split. All prior schedules kept the 8 waves symmetric: post-barrier,
// every wave bursts 12 ds_reads (+DMA) then enters MFMA -> the LDS pipe sees
// a 128 KB demand spike, queues deeply, and idles during the MFMA region
// (the ~30% no-issue stall; MfmaUtil 49 + VALUBusy 21). This round: odd
// waves run {MFMA -> prefetch-reads}, even waves {prefetch-reads -> MFMA}.
// Wave-uniform branch (s_cbranch, no exec cost); reads are next-window
// prefetch with no dependency on the current MFMA operands, so both orders
// are legal; ledger/gates/barrier identical to R8. The 2 waves/SIMD
// counter-phase: one feeds the matrix pipe while the other occupies the LDS
// pipe (m114 co-schedule; m218b setprio role-split).
//
// Ledger: prologue stages T0,T1,T2; vmcnt(4) retires T0,T1; barrier. Window
// W: stage T(W+3); vmcnt(4); {reads T(W+1) | 32 MFMA} in wv-parity order;
// barrier. Tail: W=124 stages T127; W=125 vmcnt(0); 126/127 no gate.
// Swizzle: chunk c ^ ((row>>1)&3) both-sides (0 conflicts).
// LDS: A slot s @ s*16384; B slot s @ 65536 + s*16384 (128 KiB).
// ---------------------------------------------------------------------------

#define GATE4 asm volatile("s_waitcnt vmcnt(4)" ::: "memory")
#define GATE0 asm volatile("s_waitcnt vmcnt(0)" ::: "memory")
#define NOGATE

#define DO_READS_BLK(NA_, NB_, W)                                               \
    {                                                                           \
      const int sb_ = (((W) + 1) & 3) * 16384;                                  \
      _Pragma("unroll")                                                         \
      for (int fr = 0; fr < 8; ++fr)                                            \
        NA_[fr] = *reinterpret_cast<const bf16x8*>(lds + sb_ + aOff[fr]);       \
      _Pragma("unroll")                                                         \
      for (int ni = 0; ni < 4; ++ni)                                            \
        NB_[ni] = *reinterpret_cast<const bf16x8*>(lds + 65536 + sb_ + bOff[ni]); \
    }

#define DO_MFMA_BLK(CA_, CB_)                                                   \
    __builtin_amdgcn_s_setprio(1);                                              \
    _Pragma("unroll")                                                           \
    for (int fr = 0; fr < 8; ++fr)                                              \
      _Pragma("unroll")                                                         \
      for (int ni = 0; ni < 4; ++ni)                                            \
        acc[fr][ni] = __builtin_amdgcn_mfma_f32_16x16x32_bf16(CA_[fr], CB_[ni], \
                                                              acc[fr][ni], 0, 0, 0); \
    __builtin_amdgcn_s_setprio(0);

#define WINDOW(W, CA_, CB_, NA_, NB_, DO_STAGE, GATE_STMT, DO_READS, DO_BAR)    \
  {                                                                             \
    const int w_ = (W);                                                         \
    if (DO_STAGE) {                                                             \
      const int ks_ = w_ + 3;                                                   \
      char* sA_ = lds + (ks_ & 3) * 16384;                                      \
      char* sB_ = lds + 65536 + (ks_ & 3) * 16384;                              \
      _Pragma("unroll")                                                         \
      for (int j = 0; j < 2; ++j) {                                             \
        gload_lds16(gA + ((size_t)j * 128) * H_DIM + ks_ * 32,                  \
                    (unsigned short*)(sA_ + j * 8192 + wv * 1024));             \
        gload_lds16(gB + ((size_t)j * 128) * H_DIM + ks_ * 32,                  \
                    (unsigned short*)(sB_ + j * 8192 + wv * 1024));             \
      }                                                                         \
    }                                                                           \
    GATE_STMT;                                                                  \
    if ((wv & 1) == 0) {                                                        \
      if (DO_READS) DO_READS_BLK(NA_, NB_, w_);                                 \
      DO_MFMA_BLK(CA_, CB_);                                                    \
    } else {                                                                    \
      DO_MFMA_BLK(CA_, CB_);                                                    \
      if (DO_READS) DO_READS_BLK(NA_, NB_, w_);                                 \
    }                                                                           \
    if (DO_BAR) __builtin_amdgcn_s_barrier();                                   \
  }

__global__ void __launch_bounds__(512, 2) gemm_bin_kernel(
    const unsigned short* __restrict__ xs,   // [N_ROWS][H] bf16
    const unsigned short* __restrict__ bw,   // [O][H] bf16 (row = output col)
    const float* __restrict__ rw,            // [N_ROWS][4]
    const float* __restrict__ ocs,           // [4][O]
    const float* __restrict__ bias,          // [O]
    float* __restrict__ out)                 // [N_ROWS][O]
{
    __shared__ __align__(16) char lds[131072];

    const int t  = threadIdx.x;
    const int wv = t >> 6;
    const int ln = t & 63;
    const int wr = wv >> 2;          // 0..1 -> 128-row half
    const int wc = wv & 3;           // 0..3 -> 64-col quarter

    // T1: bijective XCD swizzle (512 blocks, 512%8==0)
    const int bid = blockIdx.x;
    const int swz = (bid & 7) * 64 + (bid >> 3);
    const int rowBase = (swz >> 4) * 256;    // 32 M-tiles
    const int colBase = (swz & 15) * 256;    // 16 N-tiles

    // staging thread map: row r = t>>2, physical chunk t&3 holds logical
    // chunk (t&3)^((t>>3)&3)  [= (t&3)^((row>>1)&3)]
    const int s_r  = t >> 2;
    const int s_cl = (t & 3) ^ ((t >> 3) & 3);
    const unsigned short* gA = xs + (size_t)(rowBase + s_r) * H_DIM + s_cl * 8;
    const unsigned short* gB = bw + (size_t)(colBase + s_r) * H_DIM + s_cl * 8;

    // read-side fragment byte offsets within a slot (loop-invariant)
    int aOff[8], bOff[4];
#pragma unroll
    for (int fr = 0; fr < 8; ++fr) {
        const int row = wr * 128 + fr * 16 + (ln & 15);
        aOff[fr] = row * 64 + (((ln >> 4) ^ ((row >> 1) & 3)) << 4);
    }
#pragma unroll
    for (int ni = 0; ni < 4; ++ni) {
        const int row = wc * 64 + ni * 16 + (ln & 15);
        bOff[ni] = row * 64 + (((ln >> 4) ^ ((row >> 1) & 3)) << 4);
    }

    f32x4 acc[8][4];
#pragma unroll
    for (int i = 0; i < 8; ++i)
#pragma unroll
        for (int j = 0; j < 4; ++j) acc[i][j] = (f32x4){0.f, 0.f, 0.f, 0.f};

    // ---- prologue: stage tiles 0,1,2 (slots 0,1,2) ----
#pragma unroll
    for (int kt = 0; kt < 3; ++kt) {
        char* sA = lds + kt * 16384;
        char* sB = lds + 65536 + kt * 16384;
#pragma unroll
        for (int j = 0; j < 2; ++j) {
            gload_lds16(gA + ((size_t)j * 128) * H_DIM + kt * 32,
                        (unsigned short*)(sA + j * 8192 + wv * 1024));
            gload_lds16(gB + ((size_t)j * 128) * H_DIM + kt * 32,
                        (unsigned short*)(sB + j * 8192 + wv * 1024));
        }
    }
    GATE4;                               // retires T0,T1 (leaves T2 flying)
    __builtin_amdgcn_s_barrier();        // -> T0,T1 certified block-wide

    // preload current register set from tile 0 (slot 0)
    bf16x8 avA[8], bvA[4], avB[8], bvB[4];
#pragma unroll
    for (int fr = 0; fr < 8; ++fr)
        avA[fr] = *reinterpret_cast<const bf16x8*>(lds + aOff[fr]);
#pragma unroll
    for (int ni = 0; ni < 4; ++ni)
        bvA[ni] = *reinterpret_cast<const bf16x8*>(lds + 65536 + bOff[ni]);

    // ---- main loop: windows 0..123 (steady), 124..127 peeled ----
    for (int w = 0; w < 124; w += 2) {
        WINDOW(w,     avA, bvA, avB, bvB, 1, GATE4, 1, 1);
        WINDOW(w + 1, avB, bvB, avA, bvA, 1, GATE4, 1, 1);
    }
    WINDOW(124, avA, bvA, avB, bvB, 1, GATE4,  1, 1);   // stages T127 (last)
    WINDOW(125, avB, bvB, avA, bvA, 0, GATE0,  1, 1);   // certify T127
    WINDOW(126, avA, bvA, avB, bvB, 0, NOGATE, 1, 1);
    WINDOW(127, avB, bvB, avA, bvA, 0, NOGATE, 0, 0);

    // ---- epilogue: y = acc * (rw . ocs[:,col]) + bias ----
    float oce[4][4], bve[4];
    int cole[4];
#pragma unroll
    for (int ni = 0; ni < 4; ++ni) {
        const int col = colBase + wc * 64 + ni * 16 + (ln & 15);
        cole[ni] = col;
        oce[ni][0] = ocs[0 * O_DIM + col];
        oce[ni][1] = ocs[1 * O_DIM + col];
        oce[ni][2] = ocs[2 * O_DIM + col];
        oce[ni][3] = ocs[3 * O_DIM + col];
        bve[ni] = bias[col];
    }
#pragma unroll
    for (int fr = 0; fr < 8; ++fr) {
        float4 rwv[4];
        int rowe[4];
#pragma unroll
        for (int j = 0; j < 4; ++j) {
            const int row = rowBase + wr * 128 + fr * 16 + (ln >> 4) * 4 + j;
            rowe[j] = row;
            rwv[j] = *reinterpret_cast<const float4*>(rw + (size_t)row * 4);
        }
#pragma unroll
        for (int ni = 0; ni < 4; ++ni) {
#pragma unroll
            for (int j = 0; j < 4; ++j) {
                const float os = rwv[j].x * oce[ni][0] + rwv[j].y * oce[ni][1] +
                                 rwv[j].z * oce[ni][2] + rwv[j].w * oce[ni][3];
                out[(size_t)rowe[j] * O_DIM + cole[ni]] = acc[fr][ni][j] * os + bve[ni];
            }
        }
    }
}

// ---------------------------------------------------------------------------
extern "C" void kernel_launch(void* const* d_in, const int* in_sizes, int n_in,
                              void* d_out, int out_size, void* d_ws, size_t ws_size,
                              hipStream_t stream) {
    const float* x      = (const float*)d_in[0];
    const float* weight = (const float*)d_in[1];
    const float* bias   = (const float*)d_in[2];
    const float* gate_w = (const float*)d_in[3];
    const float* ics    = (const float*)d_in[4];
    const float* ocs    = (const float*)d_in[5];
    float* out = (float*)d_out;

    unsigned short* xs = (unsigned short*)d_ws;                      // [N][H] bf16
    unsigned short* bw = xs + (size_t)N_ROWS * H_DIM;                // [O][H] bf16
    float* rw = (float*)(bw + (size_t)O_DIM * H_DIM);                // [N][4]

    pre_kernel<<<SIGN_BLKS + N_ROWS, 256, 0, stream>>>(weight, bw, x, gate_w,
                                                       ics, rw, xs);
    gemm_bin_kernel<<<(N_ROWS / 256) * (O_DIM / 256), 512, 0, stream>>>(xs, bw, rw, ocs, bias, out);
}

// Round 12
// 314.286 us; speedup vs baseline: 9.3990x; 9.3990x over previous
//
#include <hip/hip_runtime.h>
#include <hip/hip_bf16.h>

// BinaryMoSLinear: B=4, S=2048 -> N=8192 rows; H=O=4096; E=4.
#define H_DIM 4096
#define O_DIM 4096
#define N_ROWS 8192

typedef __bf16 bf16x8 __attribute__((ext_vector_type(8)));
typedef float  f32x4  __attribute__((ext_vector_type(4)));

__device__ __forceinline__ unsigned short f32_bf16_rne(float f) {
    unsigned int u = __builtin_bit_cast(unsigned int, f);
    u += 0x7FFFu + ((u >> 16) & 1u);
    return (unsigned short)(u >> 16);
}

__device__ __forceinline__ void gload_lds16(const unsigned short* g, unsigned short* l) {
    __builtin_amdgcn_global_load_lds((const __attribute__((address_space(1))) void*)g,
                                     (__attribute__((address_space(3))) void*)l,
                                     16, 0, 0);
}

// ---------------------------------------------------------------------------
// Fused pre-kernel (R10, kept): blocks [0, SIGN_BLKS) do sign(weight)->bf16;
// blocks [SIGN_BLKS, SIGN_BLKS+N_ROWS) do router softmax + xs scale.
// ---------------------------------------------------------------------------
#define SIGN_BLKS ((O_DIM * H_DIM) / (256 * 8))   // 8192

__global__ void __launch_bounds__(256) pre_kernel(
    const float* __restrict__ w,  unsigned short* __restrict__ bw,
    const float* __restrict__ x,  const float* __restrict__ gate_w,
    const float* __restrict__ ics, float* __restrict__ rw_out,
    unsigned short* __restrict__ xs_out)
{
    const int t = threadIdx.x;

    if (blockIdx.x < SIGN_BLKS) {
        size_t i = ((size_t)blockIdx.x * 256 + t) * 8;
        float4 a = *reinterpret_cast<const float4*>(w + i);
        float4 b = *reinterpret_cast<const float4*>(w + i + 4);
        ushort4 o0, o1;
        o0.x = a.x > 0.f ? 0x3F80 : (a.x < 0.f ? 0xBF80 : 0);
        o0.y = a.y > 0.f ? 0x3F80 : (a.y < 0.f ? 0xBF80 : 0);
        o0.z = a.z > 0.f ? 0x3F80 : (a.z < 0.f ? 0xBF80 : 0);
        o0.w = a.w > 0.f ? 0x3F80 : (a.w < 0.f ? 0xBF80 : 0);
        o1.x = b.x > 0.f ? 0x3F80 : (b.x < 0.f ? 0xBF80 : 0);
        o1.y = b.y > 0.f ? 0x3F80 : (b.y < 0.f ? 0xBF80 : 0);
        o1.z = b.z > 0.f ? 0x3F80 : (b.z < 0.f ? 0xBF80 : 0);
        o1.w = b.w > 0.f ? 0x3F80 : (b.w < 0.f ? 0xBF80 : 0);
        uint4 pack;
        pack.x = (unsigned)o0.x | ((unsigned)o0.y << 16);
        pack.y = (unsigned)o0.z | ((unsigned)o0.w << 16);
        pack.z = (unsigned)o1.x | ((unsigned)o1.y << 16);
        pack.w = (unsigned)o1.z | ((unsigned)o1.w << 16);
        *reinterpret_cast<uint4*>(bw + i) = pack;
        return;
    }

    __shared__ float red[4][4];
    const int n = blockIdx.x - SIGN_BLKS;
    const float* xr = x + (size_t)n * H_DIM;

    float4 xv[4];
    float lg[4] = {0.f, 0.f, 0.f, 0.f};
#pragma unroll
    for (int c = 0; c < 4; ++c) {
        const int idx = c * 1024 + t * 4;
        xv[c] = *reinterpret_cast<const float4*>(xr + idx);
#pragma unroll
        for (int e = 0; e < 4; ++e) {
            float4 g = *reinterpret_cast<const float4*>(gate_w + e * H_DIM + idx);
            lg[e] += xv[c].x * g.x + xv[c].y * g.y + xv[c].z * g.z + xv[c].w * g.w;
        }
    }
#pragma unroll
    for (int e = 0; e < 4; ++e) {
#pragma unroll
        for (int off = 1; off < 64; off <<= 1)
            lg[e] += __shfl_xor(lg[e], off, 64);
    }
    if ((t & 63) == 0) {
        const int w_ = t >> 6;
        red[w_][0] = lg[0]; red[w_][1] = lg[1]; red[w_][2] = lg[2]; red[w_][3] = lg[3];
    }
    __syncthreads();
    const float l0 = red[0][0] + red[1][0] + red[2][0] + red[3][0];
    const float l1 = red[0][1] + red[1][1] + red[2][1] + red[3][1];
    const float l2 = red[0][2] + red[1][2] + red[2][2] + red[3][2];
    const float l3 = red[0][3] + red[1][3] + red[2][3] + red[3][3];
    const float m  = fmaxf(fmaxf(l0, l1), fmaxf(l2, l3));
    const float p0 = expf(l0 - m), p1 = expf(l1 - m), p2 = expf(l2 - m), p3 = expf(l3 - m);
    const float inv = 1.f / (p0 + p1 + p2 + p3);
    const float w0 = p0 * inv, w1 = p1 * inv, w2 = p2 * inv, w3 = p3 * inv;
    if (t == 0) {
        float4 wv = make_float4(w0, w1, w2, w3);
        *reinterpret_cast<float4*>(rw_out + (size_t)n * 4) = wv;
    }
#pragma unroll
    for (int c = 0; c < 4; ++c) {
        const int idx = c * 1024 + t * 4;
        float4 i0 = *reinterpret_cast<const float4*>(ics + 0 * H_DIM + idx);
        float4 i1 = *reinterpret_cast<const float4*>(ics + 1 * H_DIM + idx);
        float4 i2 = *reinterpret_cast<const float4*>(ics + 2 * H_DIM + idx);
        float4 i3 = *reinterpret_cast<const float4*>(ics + 3 * H_DIM + idx);
        const float sx = w0 * i0.x + w1 * i1.x + w2 * i2.x + w3 * i3.x;
        const float sy = w0 * i0.y + w1 * i1.y + w2 * i2.y + w3 * i3.y;
        const float sz = w0 * i0.z + w1 * i1.z + w2 * i2.z + w3 * i3.z;
        const float sw = w0 * i0.w + w1 * i1.w + w2 * i2.w + w3 * i3.w;
        ushort4 o;
        o.x = f32_bf16_rne(xv[c].x * sx);
        o.y = f32_bf16_rne(xv[c].y * sy);
        o.z = f32_bf16_rne(xv[c].z * sz);
        o.w = f32_bf16_rne(xv[c].w * sw);
        *reinterpret_cast<ushort4*>(xs_out + (size_t)n * H_DIM + idx) = o;
    }
}

// ---------------------------------------------------------------------------
// Kernel 3: C = (xs @ bw^T) * (rw @ ocs) + bias  — R8 structure + anti-phase
// wave split, SPILL-PROOF form. R11's per-window wv-branch spilled the
// ping-pong fragment sets to scratch (WRITE_SIZE 7.5 GB). Fix: hoist the
// parity branch OUTSIDE the K-loop — two complete straight-line loop copies
// (even waves: reads->MFMA, R8-identical; odd waves: MFMA->reads). Each copy
// allocates like R8 (128 VGPR, no spills). Both copies execute the identical
// barrier sequence, so all 8 waves meet at every s_barrier. The 2 waves/SIMD
// counter-phase: one occupies the LDS pipe while the other feeds the matrix
// pipe, halving the post-barrier LDS demand burst.
//
// Ledger (R8-verbatim in both copies): prologue stages T0,T1,T2; vmcnt(4)
// retires T0,T1; barrier. Window W: stage T(W+3); vmcnt(4); {reads T(W+1) |
// 32 MFMA} in copy order; barrier. Tail: W=124 stages T127; W=125 vmcnt(0);
// 126/127 no gate. T(W+1) certified at window W-1's gate+barrier; slot
// overwrite joins the W-1 end barrier in both orders (reads precede it).
// Swizzle: chunk c ^ ((row>>1)&3) both-sides (0 conflicts).
// LDS: A slot s @ s*16384; B slot s @ 65536 + s*16384 (128 KiB).
// ---------------------------------------------------------------------------

#define GATE4 asm volatile("s_waitcnt vmcnt(4)" ::: "memory")
#define GATE0 asm volatile("s_waitcnt vmcnt(0)" ::: "memory")
#define NOGATE

#define STAGE_BLK(W)                                                            \
    {                                                                           \
      const int ks_ = (W) + 3;                                                  \
      char* sA_ = lds + (ks_ & 3) * 16384;                                      \
      char* sB_ = lds + 65536 + (ks_ & 3) * 16384;                              \
      _Pragma("unroll")                                                         \
      for (int j = 0; j < 2; ++j) {                                             \
        gload_lds16(gA + ((size_t)j * 128) * H_DIM + ks_ * 32,                  \
                    (unsigned short*)(sA_ + j * 8192 + wv * 1024));             \
        gload_lds16(gB + ((size_t)j * 128) * H_DIM + ks_ * 32,                  \
                    (unsigned short*)(sB_ + j * 8192 + wv * 1024));             \
      }                                                                         \
    }

#define READS_BLK(NA_, NB_, W)                                                  \
    {                                                                           \
      const int sb_ = (((W) + 1) & 3) * 16384;                                  \
      _Pragma("unroll")                                                         \
      for (int fr = 0; fr < 8; ++fr)                                            \
        NA_[fr] = *reinterpret_cast<const bf16x8*>(lds + sb_ + aOff[fr]);       \
      _Pragma("unroll")                                                         \
      for (int ni = 0; ni < 4; ++ni)                                            \
        NB_[ni] = *reinterpret_cast<const bf16x8*>(lds + 65536 + sb_ + bOff[ni]); \
    }

#define MFMA_BLK(CA_, CB_)                                                      \
    __builtin_amdgcn_s_setprio(1);                                              \
    _Pragma("unroll")                                                           \
    for (int fr = 0; fr < 8; ++fr)                                              \
      _Pragma("unroll")                                                         \
      for (int ni = 0; ni < 4; ++ni)                                            \
        acc[fr][ni] = __builtin_amdgcn_mfma_f32_16x16x32_bf16(CA_[fr], CB_[ni], \
                                                              acc[fr][ni], 0, 0, 0); \
    __builtin_amdgcn_s_setprio(0);

// Window, reads-then-MFMA (R8 order) and MFMA-then-reads
#define WIN_RM(W, CA_, CB_, NA_, NB_, DO_STAGE, GATE_STMT, DO_READS, DO_BAR)    \
  { if (DO_STAGE) STAGE_BLK(W); GATE_STMT;                                      \
    if (DO_READS) READS_BLK(NA_, NB_, W);                                       \
    MFMA_BLK(CA_, CB_);                                                         \
    if (DO_BAR) __builtin_amdgcn_s_barrier(); }

#define WIN_MR(W, CA_, CB_, NA_, NB_, DO_STAGE, GATE_STMT, DO_READS, DO_BAR)    \
  { if (DO_STAGE) STAGE_BLK(W); GATE_STMT;                                      \
    MFMA_BLK(CA_, CB_);                                                         \
    if (DO_READS) READS_BLK(NA_, NB_, W);                                       \
    if (DO_BAR) __builtin_amdgcn_s_barrier(); }

__global__ void __launch_bounds__(512, 2) gemm_bin_kernel(
    const unsigned short* __restrict__ xs,   // [N_ROWS][H] bf16
    const unsigned short* __restrict__ bw,   // [O][H] bf16 (row = output col)
    const float* __restrict__ rw,            // [N_ROWS][4]
    const float* __restrict__ ocs,           // [4][O]
    const float* __restrict__ bias,          // [O]
    float* __restrict__ out)                 // [N_ROWS][O]
{
    __shared__ __align__(16) char lds[131072];

    const int t  = threadIdx.x;
    const int wv = t >> 6;
    const int ln = t & 63;
    const int wr = wv >> 2;          // 0..1 -> 128-row half
    const int wc = wv & 3;           // 0..3 -> 64-col quarter

    // T1: bijective XCD swizzle (512 blocks, 512%8==0)
    const int bid = blockIdx.x;
    const int swz = (bid & 7) * 64 + (bid >> 3);
    const int rowBase = (swz >> 4) * 256;    // 32 M-tiles
    const int colBase = (swz & 15) * 256;    // 16 N-tiles

    // staging thread map: row r = t>>2, physical chunk t&3 holds logical
    // chunk (t&3)^((t>>3)&3)  [= (t&3)^((row>>1)&3)]
    const int s_r  = t >> 2;
    const int s_cl = (t & 3) ^ ((t >> 3) & 3);
    const unsigned short* gA = xs + (size_t)(rowBase + s_r) * H_DIM + s_cl * 8;
    const unsigned short* gB = bw + (size_t)(colBase + s_r) * H_DIM + s_cl * 8;

    // read-side fragment byte offsets within a slot (loop-invariant)
    int aOff[8], bOff[4];
#pragma unroll
    for (int fr = 0; fr < 8; ++fr) {
        const int row = wr * 128 + fr * 16 + (ln & 15);
        aOff[fr] = row * 64 + (((ln >> 4) ^ ((row >> 1) & 3)) << 4);
    }
#pragma unroll
    for (int ni = 0; ni < 4; ++ni) {
        const int row = wc * 64 + ni * 16 + (ln & 15);
        bOff[ni] = row * 64 + (((ln >> 4) ^ ((row >> 1) & 3)) << 4);
    }

    f32x4 acc[8][4];
#pragma unroll
    for (int i = 0; i < 8; ++i)
#pragma unroll
        for (int j = 0; j < 4; ++j) acc[i][j] = (f32x4){0.f, 0.f, 0.f, 0.f};

    // ---- prologue: stage tiles 0,1,2 (slots 0,1,2) ----
#pragma unroll
    for (int kt = 0; kt < 3; ++kt) {
        char* sA = lds + kt * 16384;
        char* sB = lds + 65536 + kt * 16384;
#pragma unroll
        for (int j = 0; j < 2; ++j) {
            gload_lds16(gA + ((size_t)j * 128) * H_DIM + kt * 32,
                        (unsigned short*)(sA + j * 8192 + wv * 1024));
            gload_lds16(gB + ((size_t)j * 128) * H_DIM + kt * 32,
                        (unsigned short*)(sB + j * 8192 + wv * 1024));
        }
    }
    GATE4;                               // retires T0,T1 (leaves T2 flying)
    __builtin_amdgcn_s_barrier();        // -> T0,T1 certified block-wide

    // preload current register set from tile 0 (slot 0)
    bf16x8 avA[8], bvA[4], avB[8], bvB[4];
#pragma unroll
    for (int fr = 0; fr < 8; ++fr)
        avA[fr] = *reinterpret_cast<const bf16x8*>(lds + aOff[fr]);
#pragma unroll
    for (int ni = 0; ni < 4; ++ni)
        bvA[ni] = *reinterpret_cast<const bf16x8*>(lds + 65536 + bOff[ni]);

    // ---- main loop: parity branch hoisted OUTSIDE (wave-uniform, both
    //      copies execute the identical barrier sequence) ----
    if ((wv & 1) == 0) {
        for (int w = 0; w < 124; w += 2) {
            WIN_RM(w,     avA, bvA, avB, bvB, 1, GATE4, 1, 1);
            WIN_RM(w + 1, avB, bvB, avA, bvA, 1, GATE4, 1, 1);
        }
        WIN_RM(124, avA, bvA, avB, bvB, 1, GATE4,  1, 1);
        WIN_RM(125, avB, bvB, avA, bvA, 0, GATE0,  1, 1);
        WIN_RM(126, avA, bvA, avB, bvB, 0, NOGATE, 1, 1);
        WIN_RM(127, avB, bvB, avA, bvA, 0, NOGATE, 0, 0);
    } else {
        for (int w = 0; w < 124; w += 2) {
            WIN_MR(w,     avA, bvA, avB, bvB, 1, GATE4, 1, 1);
            WIN_MR(w + 1, avB, bvB, avA, bvA, 1, GATE4, 1, 1);
        }
        WIN_MR(124, avA, bvA, avB, bvB, 1, GATE4,  1, 1);
        WIN_MR(125, avB, bvB, avA, bvA, 0, GATE0,  1, 1);
        WIN_MR(126, avA, bvA, avB, bvB, 0, NOGATE, 1, 1);
        WIN_MR(127, avB, bvB, avA, bvA, 0, NOGATE, 0, 0);
    }

    // ---- epilogue: y = acc * (rw . ocs[:,col]) + bias ----
    float oce[4][4], bve[4];
    int cole[4];
#pragma unroll
    for (int ni = 0; ni < 4; ++ni) {
        const int col = colBase + wc * 64 + ni * 16 + (ln & 15);
        cole[ni] = col;
        oce[ni][0] = ocs[0 * O_DIM + col];
        oce[ni][1] = ocs[1 * O_DIM + col];
        oce[ni][2] = ocs[2 * O_DIM + col];
        oce[ni][3] = ocs[3 * O_DIM + col];
        bve[ni] = bias[col];
    }
#pragma unroll
    for (int fr = 0; fr < 8; ++fr) {
        float4 rwv[4];
        int rowe[4];
#pragma unroll
        for (int j = 0; j < 4; ++j) {
            const int row = rowBase + wr * 128 + fr * 16 + (ln >> 4) * 4 + j;
            rowe[j] = row;
            rwv[j] = *reinterpret_cast<const float4*>(rw + (size_t)row * 4);
        }
#pragma unroll
        for (int ni = 0; ni < 4; ++ni) {
#pragma unroll
            for (int j = 0; j < 4; ++j) {
                const float os = rwv[j].x * oce[ni][0] + rwv[j].y * oce[ni][1] +
                                 rwv[j].z * oce[ni][2] + rwv[j].w * oce[ni][3];
                out[(size_t)rowe[j] * O_DIM + cole[ni]] = acc[fr][ni][j] * os + bve[ni];
            }
        }
    }
}

// ---------------------------------------------------------------------------
extern "C" void kernel_launch(void* const* d_in, const int* in_sizes, int n_in,
                              void* d_out, int out_size, void* d_ws, size_t ws_size,
                              hipStream_t stream) {
    const float* x      = (const float*)d_in[0];
    const float* weight = (const float*)d_in[1];
    const float* bias   = (const float*)d_in[2];
    const float* gate_w = (const float*)d_in[3];
    const float* ics    = (const float*)d_in[4];
    const float* ocs    = (const float*)d_in[5];
    float* out = (float*)d_out;

    unsigned short* xs = (unsigned short*)d_ws;                      // [N][H] bf16
    unsigned short* bw = xs + (size_t)N_ROWS * H_DIM;                // [O][H] bf16
    float* rw = (float*)(bw + (size_t)O_DIM * H_DIM);                // [N][4]

    pre_kernel<<<SIGN_BLKS + N_ROWS, 256, 0, stream>>>(weight, bw, x, gate_w,
                                                       ics, rw, xs);
    gemm_bin_kernel<<<(N_ROWS / 256) * (O_DIM / 256), 512, 0, stream>>>(xs, bw, rw, ocs, bias, out);
}